// Round 3
// baseline (3343.391 us; speedup 1.0000x reference)
//
#include <hip/hip_runtime.h>
#include <math.h>

#define QN 8
#define CN 1024
#define DN 256
#define NROWS 32768
#define RPW 64

#define LOSS_OFF 8388608
#define IDX_OFF  8388609

// ---------------------------------------------------------------------------
// Kernel 1: normalize codebooks, store transposed: cbnt[q][k][c]
// (unchanged from rounds 1-2 — verified correct)
// ---------------------------------------------------------------------------
__global__ void rvq_normalize_cb(const float* __restrict__ cb,
                                 float* __restrict__ cbnt,
                                 float* __restrict__ out) {
    if (blockIdx.x == 0 && threadIdx.x == 0) out[LOSS_OFF] = 0.0f;
    const int wave = threadIdx.x >> 6;
    const int lane = threadIdx.x & 63;
    const int cw = blockIdx.x * 4 + wave;          // 0..8191
    const int q = cw >> 10;
    const int c = cw & (CN - 1);
    float4 v = reinterpret_cast<const float4*>(cb + (size_t)cw * DN)[lane];
    float ss = v.x * v.x + v.y * v.y + v.z * v.z + v.w * v.w;
#pragma unroll
    for (int m = 1; m < 64; m <<= 1) ss += __shfl_xor(ss, m, 64);
    const float inv = 1.0f / fmaxf(sqrtf(ss), 1e-12f);
    float* dst = cbnt + (size_t)q * (DN * CN) + (size_t)(lane * 4) * CN + c;
    dst[0 * CN] = v.x * inv;
    dst[1 * CN] = v.y * inv;
    dst[2 * CN] = v.z * inv;
    dst[3 * CN] = v.w * inv;
}

// ---------------------------------------------------------------------------
// helpers
// ---------------------------------------------------------------------------
__device__ __forceinline__ void acp16(float* lds_dst, const float* gsrc) {
    __builtin_amdgcn_global_load_lds(
        (const __attribute__((address_space(1))) unsigned int*)gsrc,
        (__attribute__((address_space(3))) unsigned int*)lds_dst, 16, 0, 0);
}
__device__ __forceinline__ void acp4(float* lds_dst, const float* gsrc) {
    __builtin_amdgcn_global_load_lds(
        (const __attribute__((address_space(1))) unsigned int*)gsrc,
        (__attribute__((address_space(3))) unsigned int*)lds_dst, 4, 0, 0);
}
__device__ __forceinline__ float rlf(float v, int lane) {
    return __int_as_float(__builtin_amdgcn_readlane(__float_as_int(v), lane));
}

#define DECL_ROW(j) float4 aA##j = make_float4(0.f,0.f,0.f,0.f), \
                           aB##j = make_float4(0.f,0.f,0.f,0.f);

#define FMA_ROW(j, S) \
    aA##j.x = fmaf(S, b0.x, aA##j.x); aA##j.y = fmaf(S, b0.y, aA##j.y); \
    aA##j.z = fmaf(S, b0.z, aA##j.z); aA##j.w = fmaf(S, b0.w, aA##j.w); \
    aB##j.x = fmaf(S, b1.x, aB##j.x); aB##j.y = fmaf(S, b1.y, aB##j.y); \
    aB##j.z = fmaf(S, b1.z, aB##j.z); aB##j.w = fmaf(S, b1.w, aB##j.w);

// A[kk][w*8+j]: source lane holds 4 rows per float4 component set.
#define KKSTEP(kk, AV) { \
    const int L0 = (((kk) & 3) << 4) + w2; \
    const float s0 = rlf(AV.x, L0),     s1 = rlf(AV.y, L0); \
    const float s2 = rlf(AV.z, L0),     s3 = rlf(AV.w, L0); \
    const float s4 = rlf(AV.x, L0 + 1), s5 = rlf(AV.y, L0 + 1); \
    const float s6 = rlf(AV.z, L0 + 1), s7 = rlf(AV.w, L0 + 1); \
    const float4 b0 = *reinterpret_cast<const float4*>(bptr + (kk) * 512 + tx4); \
    const float4 b1 = *reinterpret_cast<const float4*>(bptr + (kk) * 512 + 256 + tx4); \
    FMA_ROW(0, s0) FMA_ROW(1, s1) FMA_ROW(2, s2) FMA_ROW(3, s3) \
    FMA_ROW(4, s4) FMA_ROW(5, s5) FMA_ROW(6, s6) FMA_ROW(7, s7) }

// ascending cod order within lane (cgb+0..3 then +256..259); strict > keeps first
#define FOLDROW(j) { \
    if (aA##j.x > rv##j) { rv##j = aA##j.x; ri##j = cgbase + 0; } \
    if (aA##j.y > rv##j) { rv##j = aA##j.y; ri##j = cgbase + 1; } \
    if (aA##j.z > rv##j) { rv##j = aA##j.z; ri##j = cgbase + 2; } \
    if (aA##j.w > rv##j) { rv##j = aA##j.w; ri##j = cgbase + 3; } \
    if (aB##j.x > rv##j) { rv##j = aB##j.x; ri##j = cgbase + 256; } \
    if (aB##j.y > rv##j) { rv##j = aB##j.y; ri##j = cgbase + 257; } \
    if (aB##j.z > rv##j) { rv##j = aB##j.z; ri##j = cgbase + 258; } \
    if (aB##j.w > rv##j) { rv##j = aB##j.w; ri##j = cgbase + 259; } }

#define BFLY(j) { \
    _Pragma("unroll") \
    for (int m = 1; m < 64; m <<= 1) { \
        const float ov = __shfl_xor(rv##j, m, 64); \
        const int   oi = __shfl_xor(ri##j, m, 64); \
        if (ov > rv##j || (ov == rv##j && oi < ri##j)) { rv##j = ov; ri##j = oi; } } }

#define STAGE_B(nb, tile) { \
    const float* s_ = cbtq + (size_t)(((tile) * 8 + w) * 1024) + coff + tx4; \
    acp16(&Btl[nb][w][tx4], s_); \
    acp16(&Btl[nb][w][256 + tx4], s_ + 256); }

#define STAGE_A(nb, tile) \
    acp4(&At2[nb][(w << 6) + lane], residG + (tile) * 512 + (w << 6) + lane);

#define FIN(F, JB) { \
    size_t o_ = (size_t)(base + rb + (JB)) * DN + kcol; \
    out[o_] = in[o_] - F.x; o_ += DN; \
    out[o_] = in[o_] - F.y; o_ += DN; \
    out[o_] = in[o_] - F.z; o_ += DN; \
    out[o_] = in[o_] - F.w; }

// ---------------------------------------------------------------------------
// Kernel 2: persistent RVQ. 512-thread WG owns 64 rows through all 8 stages.
// Residual lives in the out-buffer region ([k][row] per-WG block), staged
// per-8k-tile; A broadcast via v_readlane; B double-buffered in LDS.
// fmaf chain per (row,cod) is k=0..255 sequential — bit-identical to rounds 1-2.
// ---------------------------------------------------------------------------
__global__ __launch_bounds__(512, 4)
void rvq_main(const float* __restrict__ in,
              const float* __restrict__ cb,
              const float* __restrict__ cbnt,
              float* __restrict__ out) {
    __shared__ float Btl[2][8][512];   // 32 KiB: B k-tiles (8k x 512 cods), dbuf
    __shared__ float At2[2][512];      // 4 KiB:  A k-tiles (8k x 64 rows), dbuf
    __shared__ int   sIdx[64];
    __shared__ float red[8];

    const int t    = threadIdx.x;
    const int lane = t & 63;
    const int w    = t >> 6;           // wave id 0..7 == GEMM row-group
    const int w2   = w << 1;
    const int tx4  = lane << 2;
    const int base = blockIdx.x * RPW;
    float* residG  = out + (size_t)base * DN;   // WG-private 16384-float block

    // ---- init: resid[k][row] = in[base+row][k] (transpose into out region)
    {
        const int row = t >> 3;
        const int kc  = (t & 7) << 5;
        const float* src = in + (size_t)(base + row) * DN + kc;
#pragma unroll
        for (int jb = 0; jb < 8; ++jb) {
            const float4 f = *reinterpret_cast<const float4*>(src + jb * 4);
            residG[(kc + jb * 4 + 0) * 64 + row] = f.x;
            residG[(kc + jb * 4 + 1) * 64 + row] = f.y;
            residG[(kc + jb * 4 + 2) * 64 + row] = f.z;
            residG[(kc + jb * 4 + 3) * 64 + row] = f.w;
        }
    }
    __threadfence();
    __syncthreads();

    float lossAcc = 0.0f;

    for (int q = 0; q < QN; ++q) {
        const float* cbtq = cbnt + (size_t)q * (DN * CN);
        float rv0 = -INFINITY, rv1 = -INFINITY, rv2 = -INFINITY, rv3 = -INFINITY,
              rv4 = -INFINITY, rv5 = -INFINITY, rv6 = -INFINITY, rv7 = -INFINITY;
        int ri0 = 0, ri1 = 0, ri2 = 0, ri3 = 0, ri4 = 0, ri5 = 0, ri6 = 0, ri7 = 0;

        for (int chunk = 0; chunk < 2; ++chunk) {     // 2 x 512 cods
            const int coff   = chunk << 9;
            const int cgbase = coff + tx4;
            DECL_ROW(0) DECL_ROW(1) DECL_ROW(2) DECL_ROW(3)
            DECL_ROW(4) DECL_ROW(5) DECL_ROW(6) DECL_ROW(7)

            STAGE_B(0, 0)
            STAGE_A(0, 0)

            for (int tt = 0; tt < 32; ++tt) {          // 32 tiles x 8 k
                __syncthreads();                        // vmcnt drained: buf[tt&1] ready
                const int bb = tt & 1;
                if (tt < 31) { STAGE_B(bb ^ 1, tt + 1)  STAGE_A(bb ^ 1, tt + 1) }
                const float* bptr = &Btl[bb][0][0];
                const float4 a0 = *reinterpret_cast<const float4*>(&At2[bb][tx4]);
                const float4 a1 = *reinterpret_cast<const float4*>(&At2[bb][256 + tx4]);
                KKSTEP(0, a0) KKSTEP(1, a0) KKSTEP(2, a0) KKSTEP(3, a0)
                KKSTEP(4, a1) KKSTEP(5, a1) KKSTEP(6, a1) KKSTEP(7, a1)
            }

            FOLDROW(0) FOLDROW(1) FOLDROW(2) FOLDROW(3)
            FOLDROW(4) FOLDROW(5) FOLDROW(6) FOLDROW(7)
        }

        BFLY(0) BFLY(1) BFLY(2) BFLY(3) BFLY(4) BFLY(5) BFLY(6) BFLY(7)
        if (lane == 0) {
            sIdx[w * 8 + 0] = ri0; sIdx[w * 8 + 1] = ri1;
            sIdx[w * 8 + 2] = ri2; sIdx[w * 8 + 3] = ri3;
            sIdx[w * 8 + 4] = ri4; sIdx[w * 8 + 5] = ri5;
            sIdx[w * 8 + 6] = ri6; sIdx[w * 8 + 7] = ri7;
        }
        __syncthreads();
        if (t < 64) out[(size_t)IDX_OFF + (size_t)q * NROWS + base + t] = (float)sIdx[t];

        // residual update + loss: wave w handles k in [w*32, w*32+32), all 64 rows
        {
            const int r  = lane;
            const int gi = sIdx[r];
            const float* qrow = cb + (size_t)q * (CN * DN) + (size_t)gi * DN + (w << 5);
#pragma unroll
            for (int jb = 0; jb < 8; ++jb) {
                const float4 qv = *reinterpret_cast<const float4*>(qrow + jb * 4);
                const int k0 = (w << 5) + jb * 4;
                int id;
                id = (k0 + 0) * 64 + r; const float v0 = residG[id] - qv.x; residG[id] = v0;
                id = (k0 + 1) * 64 + r; const float v1 = residG[id] - qv.y; residG[id] = v1;
                id = (k0 + 2) * 64 + r; const float v2 = residG[id] - qv.z; residG[id] = v2;
                id = (k0 + 3) * 64 + r; const float v3 = residG[id] - qv.w; residG[id] = v3;
                lossAcc += v0 * v0 + v1 * v1 + v2 * v2 + v3 * v3;
            }
        }
        __threadfence();        // make residual stores visible past L1 for next stage's loads
        __syncthreads();
    }

    // ---- final: quantized = in - residual (in-place transpose via regs + barrier)
    {
        const float* rsrc = residG + t * 32;
        const float4 f0 = *reinterpret_cast<const float4*>(rsrc + 0);
        const float4 f1 = *reinterpret_cast<const float4*>(rsrc + 4);
        const float4 f2 = *reinterpret_cast<const float4*>(rsrc + 8);
        const float4 f3 = *reinterpret_cast<const float4*>(rsrc + 12);
        const float4 f4 = *reinterpret_cast<const float4*>(rsrc + 16);
        const float4 f5 = *reinterpret_cast<const float4*>(rsrc + 20);
        const float4 f6 = *reinterpret_cast<const float4*>(rsrc + 24);
        const float4 f7 = *reinterpret_cast<const float4*>(rsrc + 28);
        __syncthreads();                       // all resid reads complete before any write
        const int kcol = t >> 1;
        const int rb   = (t & 1) << 5;
        FIN(f0, 0) FIN(f1, 4) FIN(f2, 8)  FIN(f3, 12)
        FIN(f4, 16) FIN(f5, 20) FIN(f6, 24) FIN(f7, 28)
    }

    // ---- loss: wave butterfly + cross-wave + one atomic per WG
#pragma unroll
    for (int m = 1; m < 64; m <<= 1) lossAcc += __shfl_xor(lossAcc, m, 64);
    if (lane == 0) red[w] = lossAcc;
    __syncthreads();
    if (t == 0) {
        const float tot = red[0] + red[1] + red[2] + red[3]
                        + red[4] + red[5] + red[6] + red[7];
        atomicAdd(out + LOSS_OFF, tot * (1.25f / (8.0f * 8388608.0f)));
    }
}

extern "C" void kernel_launch(void* const* d_in, const int* in_sizes, int n_in,
                              void* d_out, int out_size, void* d_ws, size_t ws_size,
                              hipStream_t stream) {
    (void)in_sizes; (void)n_in; (void)out_size; (void)ws_size;
    const float* in   = (const float*)d_in[0];
    const float* cb   = (const float*)d_in[1];
    float* out        = (float*)d_out;
    float* cbnt       = (float*)d_ws;   // 8 MiB scratch: normalized+transposed codebooks

    rvq_normalize_cb<<<dim3(2048), dim3(256), 0, stream>>>(cb, cbnt, out);
    rvq_main<<<dim3(512), dim3(512), 0, stream>>>(in, cb, cbnt, out);
}

// Round 4
// 1686.172 us; speedup vs baseline: 1.9828x; 1.9828x over previous
//
#include <hip/hip_runtime.h>
#include <math.h>

#define QN 8
#define CN 1024
#define DN 256
#define NROWS 32768
#define RPW 64

#define LOSS_OFF 8388608
#define IDX_OFF  8388609

// ---------------------------------------------------------------------------
// Kernel 1: normalize codebooks, store transposed: cbnt[q][k][c]
// (unchanged from rounds 1-3 — verified correct)
// ---------------------------------------------------------------------------
__global__ void rvq_normalize_cb(const float* __restrict__ cb,
                                 float* __restrict__ cbnt,
                                 float* __restrict__ out) {
    if (blockIdx.x == 0 && threadIdx.x == 0) out[LOSS_OFF] = 0.0f;
    const int wave = threadIdx.x >> 6;
    const int lane = threadIdx.x & 63;
    const int cw = blockIdx.x * 4 + wave;          // 0..8191
    const int q = cw >> 10;
    const int c = cw & (CN - 1);
    float4 v = reinterpret_cast<const float4*>(cb + (size_t)cw * DN)[lane];
    float ss = v.x * v.x + v.y * v.y + v.z * v.z + v.w * v.w;
#pragma unroll
    for (int m = 1; m < 64; m <<= 1) ss += __shfl_xor(ss, m, 64);
    const float inv = 1.0f / fmaxf(sqrtf(ss), 1e-12f);
    float* dst = cbnt + (size_t)q * (DN * CN) + (size_t)(lane * 4) * CN + c;
    dst[0 * CN] = v.x * inv;
    dst[1 * CN] = v.y * inv;
    dst[2 * CN] = v.z * inv;
    dst[3 * CN] = v.w * inv;
}

// ---------------------------------------------------------------------------
// async global->LDS, 16B per lane (dest = wave-uniform base + lane*16)
// ---------------------------------------------------------------------------
__device__ __forceinline__ void acp16(float* lds_dst, const float* gsrc) {
    __builtin_amdgcn_global_load_lds(
        (const __attribute__((address_space(1))) unsigned int*)gsrc,
        (__attribute__((address_space(3))) unsigned int*)lds_dst, 16, 0, 0);
}

// 8 rows x 16 cods per thread, all accumulators individually named
#define DECL_ROW(j) \
    float4 c##j##_0 = make_float4(0.f,0.f,0.f,0.f), \
           c##j##_1 = make_float4(0.f,0.f,0.f,0.f), \
           c##j##_2 = make_float4(0.f,0.f,0.f,0.f), \
           c##j##_3 = make_float4(0.f,0.f,0.f,0.f);

#define FMA_ROW(j, S) \
    c##j##_0.x = fmaf(S, b0.x, c##j##_0.x); c##j##_0.y = fmaf(S, b0.y, c##j##_0.y); \
    c##j##_0.z = fmaf(S, b0.z, c##j##_0.z); c##j##_0.w = fmaf(S, b0.w, c##j##_0.w); \
    c##j##_1.x = fmaf(S, b1.x, c##j##_1.x); c##j##_1.y = fmaf(S, b1.y, c##j##_1.y); \
    c##j##_1.z = fmaf(S, b1.z, c##j##_1.z); c##j##_1.w = fmaf(S, b1.w, c##j##_1.w); \
    c##j##_2.x = fmaf(S, b2.x, c##j##_2.x); c##j##_2.y = fmaf(S, b2.y, c##j##_2.y); \
    c##j##_2.z = fmaf(S, b2.z, c##j##_2.z); c##j##_2.w = fmaf(S, b2.w, c##j##_2.w); \
    c##j##_3.x = fmaf(S, b3.x, c##j##_3.x); c##j##_3.y = fmaf(S, b3.y, c##j##_3.y); \
    c##j##_3.z = fmaf(S, b3.z, c##j##_3.z); c##j##_3.w = fmaf(S, b3.w, c##j##_3.w);

#define KKSTEP(kk) { \
    const float4 a0 = *reinterpret_cast<const float4*>(&At[kt4 + (kk)][ty8]); \
    const float4 a1 = *reinterpret_cast<const float4*>(&At[kt4 + (kk)][ty8 + 4]); \
    const float4 b0 = *reinterpret_cast<const float4*>(&Btl[bb][kk][tx4]); \
    const float4 b1 = *reinterpret_cast<const float4*>(&Btl[bb][kk][128 + tx4]); \
    const float4 b2 = *reinterpret_cast<const float4*>(&Btl[bb][kk][256 + tx4]); \
    const float4 b3 = *reinterpret_cast<const float4*>(&Btl[bb][kk][384 + tx4]); \
    FMA_ROW(0, a0.x) FMA_ROW(1, a0.y) FMA_ROW(2, a0.z) FMA_ROW(3, a0.w) \
    FMA_ROW(4, a1.x) FMA_ROW(5, a1.y) FMA_ROW(6, a1.z) FMA_ROW(7, a1.w) }

// within-thread cods ascend: q*128 + tx*4 + e for q=0..3; strict > keeps first max
#define FOLD_Q(j, qq) { \
    const int cb_ = coff + (qq) * 128 + tx4; \
    if (c##j##_##qq.x > bv) { bv = c##j##_##qq.x; bi = cb_ + 0; } \
    if (c##j##_##qq.y > bv) { bv = c##j##_##qq.y; bi = cb_ + 1; } \
    if (c##j##_##qq.z > bv) { bv = c##j##_##qq.z; bi = cb_ + 2; } \
    if (c##j##_##qq.w > bv) { bv = c##j##_##qq.w; bi = cb_ + 3; } }

// butterfly over the 32 tx lanes (xor masks 1..16 stay within the half-wave)
#define FOLDMERGE(j) { \
    float bv = -INFINITY; int bi = 0; \
    FOLD_Q(j, 0) FOLD_Q(j, 1) FOLD_Q(j, 2) FOLD_Q(j, 3) \
    _Pragma("unroll") \
    for (int m = 1; m < 32; m <<= 1) { \
        const float ov = __shfl_xor(bv, m, 64); \
        const int   oi = __shfl_xor(bi, m, 64); \
        if (ov > bv || (ov == bv && oi < bi)) { bv = ov; bi = oi; } } \
    if (bv > rv##j) { rv##j = bv; ri##j = bi; } }

// stage one 4k x 512c B-tile (8 KiB): 2 x acp16 per thread, linear LDS dest
#define STAGE(nb, tile) { \
    const float* s_ = cbtq + (size_t)(((tile) * 4 + (t >> 7)) * 1024) + coff + ((t * 4) & 511); \
    acp16(Bflat + (nb) * 2048 + t * 4, s_); \
    acp16(Bflat + (nb) * 2048 + 1024 + t * 4, s_ + 2048); }

// ---------------------------------------------------------------------------
// Kernel 2: persistent RVQ, 256-thread WG owns 64 rows through all 8 stages.
// Residual in LDS At[k][row] (round-2 structure); B double-buffered 4k-tiles.
// Per-thread tile 8 rows x 16 cods -> 6 ds_read_b128 per 128 FMA.
// fmaf chain per (row,cod) is k=0..255 sequential — bit-identical to round 2.
// ---------------------------------------------------------------------------
__global__ __attribute__((amdgpu_flat_work_group_size(256, 256), amdgpu_waves_per_eu(2, 2)))
void rvq_main(const float* __restrict__ in,
              const float* __restrict__ cb,
              const float* __restrict__ cbnt,
              float* __restrict__ out) {
    __shared__ float At[DN][RPW];       // 64 KiB residual, transposed [k][row]
    __shared__ float Btl[2][4][512];    // 16 KiB: dbuf of 4k x 512c tiles
    float* Bflat = &Btl[0][0][0];
    int*   sIdx  = reinterpret_cast<int*>(Bflat);        // alias (64 ints)
    float* red   = Bflat + 64;                           // alias (4 floats)

    const int t    = threadIdx.x;
    const int lane = t & 63;
    const int kgrp = t >> 6;            // wave id 0..3 (elementwise phases)
    const int ty8  = (t >> 5) << 3;     // row-group base: 8 groups x 8 rows
    const int tx4  = (t & 31) << 2;     // cod-group base within 512-chunk
    const int tx   = t & 31;
    const int base = blockIdx.x * RPW;

    // residual := inputs (At writes 2-way bank aliased = free)
#pragma unroll
    for (int i = 0; i < 16; ++i) {
        const int kb = kgrp * 4 + i * 16;
        float4 v = *reinterpret_cast<const float4*>(in + (size_t)(base + lane) * DN + kb);
        At[kb + 0][lane] = v.x;
        At[kb + 1][lane] = v.y;
        At[kb + 2][lane] = v.z;
        At[kb + 3][lane] = v.w;
    }

    float lossAcc = 0.0f;

    for (int q = 0; q < QN; ++q) {
        const float* cbq  = cb   + (size_t)q * (CN * DN);
        const float* cbtq = cbnt + (size_t)q * (DN * CN);
        float rv0 = -INFINITY, rv1 = -INFINITY, rv2 = -INFINITY, rv3 = -INFINITY,
              rv4 = -INFINITY, rv5 = -INFINITY, rv6 = -INFINITY, rv7 = -INFINITY;
        int ri0 = 0, ri1 = 0, ri2 = 0, ri3 = 0, ri4 = 0, ri5 = 0, ri6 = 0, ri7 = 0;

        for (int chunk = 0; chunk < 2; ++chunk) {        // 2 x 512 cods
            const int coff = chunk << 9;
            DECL_ROW(0) DECL_ROW(1) DECL_ROW(2) DECL_ROW(3)
            DECL_ROW(4) DECL_ROW(5) DECL_ROW(6) DECL_ROW(7)

            STAGE(0, 0)                                  // prologue: tile 0 -> buf 0

            for (int tt = 0; tt < 64; ++tt) {            // 64 tiles x 4 k
                __syncthreads();                          // vmcnt drained: buf[tt&1] ready
                const int bb = tt & 1;
                if (tt < 63) STAGE(bb ^ 1, tt + 1)        // next tile; hides under FMAs
                const int kt4 = tt * 4;
                KKSTEP(0) KKSTEP(1) KKSTEP(2) KKSTEP(3)
            }

            FOLDMERGE(0) FOLDMERGE(1) FOLDMERGE(2) FOLDMERGE(3)
            FOLDMERGE(4) FOLDMERGE(5) FOLDMERGE(6) FOLDMERGE(7)
        }

        __syncthreads();                 // all Btl reads done before alias write
        if (tx == 0) {
            sIdx[(ty8 >> 3) * 8 + 0] = ri0;  // == sIdx[ty8 + j], ty8 already *8
            sIdx[ty8 + 1] = ri1; sIdx[ty8 + 2] = ri2; sIdx[ty8 + 3] = ri3;
            sIdx[ty8 + 4] = ri4; sIdx[ty8 + 5] = ri5;
            sIdx[ty8 + 6] = ri6; sIdx[ty8 + 7] = ri7;
        }
        __syncthreads();
        if (t < 64) out[(size_t)IDX_OFF + (size_t)q * NROWS + base + t] = (float)sIdx[t];

        // residual update + loss: r_new = r - cb[idx]; loss += r_new^2
        {
            const int gi = sIdx[lane];
            const float* qrow = cbq + (size_t)gi * DN;
#pragma unroll
            for (int i = 0; i < 16; ++i) {
                const int kb = kgrp * 4 + i * 16;
                const float4 qv = *reinterpret_cast<const float4*>(qrow + kb);
                const float r0 = At[kb + 0][lane] - qv.x;
                const float r1 = At[kb + 1][lane] - qv.y;
                const float r2 = At[kb + 2][lane] - qv.z;
                const float r3 = At[kb + 3][lane] - qv.w;
                At[kb + 0][lane] = r0;
                At[kb + 1][lane] = r1;
                At[kb + 2][lane] = r2;
                At[kb + 3][lane] = r3;
                lossAcc += r0 * r0 + r1 * r1 + r2 * r2 + r3 * r3;
            }
        }
        __syncthreads();                 // At updated + sIdx free before next stage
    }

    // quantized_sum = inputs - residual_final
#pragma unroll
    for (int i = 0; i < 16; ++i) {
        const int kb = kgrp * 4 + i * 16;
        const float4 v = *reinterpret_cast<const float4*>(in + (size_t)(base + lane) * DN + kb);
        float4 o;
        o.x = v.x - At[kb + 0][lane];
        o.y = v.y - At[kb + 1][lane];
        o.z = v.z - At[kb + 2][lane];
        o.w = v.w - At[kb + 3][lane];
        *reinterpret_cast<float4*>(out + (size_t)(base + lane) * DN + kb) = o;
    }

    // loss: wave butterfly + cross-wave via LDS + one atomic per WG
#pragma unroll
    for (int m = 1; m < 64; m <<= 1) lossAcc += __shfl_xor(lossAcc, m, 64);
    __syncthreads();
    if (lane == 0) red[kgrp] = lossAcc;
    __syncthreads();
    if (t == 0) {
        const float tot = red[0] + red[1] + red[2] + red[3];
        atomicAdd(out + LOSS_OFF, tot * (1.25f / (8.0f * 8388608.0f)));
    }
}

extern "C" void kernel_launch(void* const* d_in, const int* in_sizes, int n_in,
                              void* d_out, int out_size, void* d_ws, size_t ws_size,
                              hipStream_t stream) {
    (void)in_sizes; (void)n_in; (void)out_size; (void)ws_size;
    const float* in   = (const float*)d_in[0];
    const float* cb   = (const float*)d_in[1];
    float* out        = (float*)d_out;
    float* cbnt       = (float*)d_ws;   // 8 MiB scratch: normalized+transposed codebooks

    rvq_normalize_cb<<<dim3(2048), dim3(256), 0, stream>>>(cb, cbnt, out);
    rvq_main<<<dim3(512), dim3(256), 0, stream>>>(in, cb, cbnt, out);
}